// Round 18
// baseline (80.647 us; speedup 1.0000x reference)
//
#include <hip/hip_runtime.h>
#include <stdint.h>

// N=M=16384, D=64 fp32. dist[n,m]=a_sq[n]+b_sq[m]-2ab; out = sum_n min_m.
// R15/16: i8 32x32x32 exact-integer path -> main ~25us; R17 prefetch neutral.
// R18: 16x16x64 i8 -- K=64 in ONE MFMA: no MFMA->MFMA deps (C=cinit, fresh D
// each), acc 4 regs not 16, min-tree 4 ops not 15, bsqi natural-order
// broadcast loads. ~65 regs -> launch_bounds(256,5) -> 5 blocks/CU (20
// waves/CU, LDS 5x32KB=160KB exact). Floor 8.7us of i8 pipe.
#define N_PTS 16384
#define TSPLITS 32
#define ATILES 32                    // 512 TO per ts = 32 tiles of 16
#define NBLOCKS (TSPLITS * 32)       // 32 ts x 32 bg = 1024 blocks

typedef __attribute__((ext_vector_type(4))) int i32x4;

__device__ __forceinline__ int imin(int a, int b) { return a < b ? a : b; }
__device__ __forceinline__ int q8(float x) {   // round-nearest, clamp
    int q = __float2int_rn(x);
    return q < -127 ? -127 : (q > 127 ? 127 : q);
}

// ---------- prep: fp32 -> i8 FRAGMENT-ORDER operands + norms --------------
// mfma_i32_16x16x64_i8 fragment: point p -> subtile st=p>>4, m=p&15;
// dim d -> quad qg=d>>4, byte j=d&15. offset = ((st*64)+(qg*16+m))*16 + j.
// Thread (row, sub 0..7) owns dims 8sub..8sub+7: qg=sub>>1, halfj=sub&1.
__global__ __launch_bounds__(256) void prep_kernel(
        const float* __restrict__ from_pts, const float* __restrict__ to_pts,
        float* __restrict__ a_sq, int* __restrict__ bsqi,
        char* __restrict__ BfQ, char* __restrict__ AtoQ,
        float* __restrict__ out) {
    int gid = blockIdx.x * 256 + threadIdx.x;   // 0 .. 524287
    int row = gid >> 3;                 // 0..32767 (FROM then TO)
    int sub = gid & 7;
    bool isFrom = row < N_PTS;
    int r = row & (N_PTS - 1);
    const float* src = isFrom ? from_pts : to_pts;
    float4 v0 = ((const float4*)src)[r * 16 + sub * 2];
    float4 v1 = ((const float4*)src)[r * 16 + sub * 2 + 1];
    float s = v0.x*v0.x + v0.y*v0.y + v0.z*v0.z + v0.w*v0.w
            + v1.x*v1.x + v1.y*v1.y + v1.z*v1.z + v1.w*v1.w;
    s += __shfl_xor(s, 1); s += __shfl_xor(s, 2); s += __shfl_xor(s, 4);
    float sc = isFrom ? -16.0f : 16.0f;  // FROM carries the minus sign
    int q0 = q8(v0.x*sc), q1 = q8(v0.y*sc), q2 = q8(v0.z*sc), q3 = q8(v0.w*sc);
    int q4 = q8(v1.x*sc), q5 = q8(v1.y*sc), q6 = q8(v1.z*sc), q7 = q8(v1.w*sc);
    int2 w;
    w.x = (q0 & 255) | ((q1 & 255) << 8) | ((q2 & 255) << 16) | (q3 << 24);
    w.y = (q4 & 255) | ((q5 & 255) << 8) | ((q6 & 255) << 16) | (q7 << 24);
    int st = r >> 4;                    // 16-pt subtile (0..1023)
    int m  = r & 15;
    int qg = sub >> 1, halfj = sub & 1;
    size_t off = (((size_t)st * 64) + qg * 16 + m) * 16 + 8 * halfj;
    if (isFrom) {
        *(int2*)(BfQ + off) = w;
        if (sub == 0) a_sq[r] = s;
    } else {
        *(int2*)(AtoQ + off) = w;
        // C/D row=(lane>>4)*4+reg is natural order -> no permutation
        if (sub == 0) bsqi[r] = __float2int_rn(128.0f * s);
    }
    if (gid == 0) out[0] = 0.0f;
}

// ---------- main: stage-once LDS, dep-free 16x16x64 i8 sweep --------------
__global__ __launch_bounds__(256, 5) void main_kernel(
        const char* __restrict__ BfQ, const char* __restrict__ AtoQ,
        const int* __restrict__ bsqi, int* __restrict__ pmin) {
    // whole ts A-slice: 32 tiles x 1KB = 32 KB (5 blocks/CU = 160KB exact)
    __shared__ __align__(16) char abuf[32768];

    const int tid = threadIdx.x;
    const int lane = tid & 63;
    const int wv  = tid >> 6;           // wave 0..3
    const int ts  = blockIdx.x >> 5;    // 0..31
    const int bg  = blockIdx.x & 31;    // 512 FROM per block
    const int gst = ts * ATILES;        // global TO-subtile base

    // stage: 32 chunks of 1KB; wave wv DMAs chunks 8wv..8wv+7
    // (dest = wave-uniform base + lane*16 per the global_load_lds rule)
    #pragma unroll
    for (int j2 = 0; j2 < 8; j2++) {
        int j = wv * 8 + j2;                         // 0..31
        const char* g = AtoQ + ((size_t)(gst + j) * 64 + lane) * 16;
        char* l = &abuf[j * 1024];
        __builtin_amdgcn_global_load_lds(
            (const __attribute__((address_space(1))) unsigned int*)g,
            (__attribute__((address_space(3))) unsigned int*)l, 16, 0, 0);
    }
    __syncthreads();                    // the ONLY barrier

    // 8 resident FROM subtiles (128 FROM pts): sg = bg*32 + wv*8 + j
    const int sgb = bg * 32 + wv * 8;
    i32x4 B[8];
    #pragma unroll
    for (int j = 0; j < 8; j++)
        B[j] = *(const i32x4*)(BfQ + ((size_t)(sgb + j) * 64 + lane) * 16);

    int rmin[8];
    #pragma unroll
    for (int j = 0; j < 8; j++) rmin[j] = 0x7FFFFFFF;

    const int qg4 = (lane >> 4) * 4;    // this lane's C/D row group

    #pragma unroll 2
    for (int t = 0; t < ATILES; t++) {
        // A-tile fragment: ONE ds_read_b128
        i32x4 A = *(const i32x4*)&abuf[t * 1024 + lane * 16];
        // cinit = 128*bsq rows of this tile (natural order, 16-way bcast)
        i32x4 cu = *(const i32x4*)(bsqi + (gst + t) * 16 + qg4);
        #pragma unroll
        for (int j = 0; j < 8; j++) {
            i32x4 acc = __builtin_amdgcn_mfma_i32_16x16x64_i8(A, B[j], cu, 0, 0, 0);
            rmin[j] = imin(rmin[j],
                           imin(imin(acc[0], acc[1]), imin(acc[2], acc[3])));
        }
    }

    // cross-lane: min over the 4 row-groups (lane>>4) sharing each col
    #pragma unroll
    for (int j = 0; j < 8; j++) {
        rmin[j] = imin(rmin[j], __shfl_xor(rmin[j], 16));
        rmin[j] = imin(rmin[j], __shfl_xor(rmin[j], 32));
    }
    if (lane < 16) {
        #pragma unroll
        for (int j = 0; j < 8; j++)
            pmin[(size_t)ts * N_PTS + (sgb + j) * 16 + lane] = rmin[j];
    }
}

// ---------- finish: min over 32 splits, add a_sq, global sum --------------
__global__ __launch_bounds__(256) void finish_kernel(
        const float* __restrict__ a_sq, const int* __restrict__ pmin,
        float* __restrict__ out) {
    int r = blockIdx.x * 256 + threadIdx.x;
    int m = pmin[r];
    #pragma unroll
    for (int s = 1; s < TSPLITS; s++)
        m = imin(m, pmin[(size_t)s * N_PTS + r]);
    float v = a_sq[r] + (float)m * 0.0078125f;   // /128
    #pragma unroll
    for (int k = 1; k < 64; k <<= 1) v += __shfl_xor(v, k);
    __shared__ float red[4];
    if ((threadIdx.x & 63) == 0) red[threadIdx.x >> 6] = v;
    __syncthreads();
    if (threadIdx.x == 0)
        atomicAdd(out, red[0] + red[1] + red[2] + red[3]);
}

extern "C" void kernel_launch(void* const* d_in, const int* in_sizes, int n_in,
                              void* d_out, int out_size, void* d_ws, size_t ws_size,
                              hipStream_t stream) {
    const float* from_pts = (const float*)d_in[0];
    const float* to_pts   = (const float*)d_in[1];
    char* ws = (char*)d_ws;
    float* a_sq = (float*)ws;                                  //  64 KB
    int*   bsqi = (int*)(ws + (64 << 10));                     //  64 KB
    int*   pmin = (int*)(ws + (128 << 10));                    //   2 MB
    char*  BfQ  = ws + (128 << 10) + (2 << 20);                //   1 MB
    char*  AtoQ = ws + (128 << 10) + (3 << 20);                //   1 MB

    prep_kernel<<<(2 * N_PTS * 8) / 256, 256, 0, stream>>>(
        from_pts, to_pts, a_sq, bsqi, BfQ, AtoQ, (float*)d_out);
    main_kernel<<<NBLOCKS, 256, 0, stream>>>(BfQ, AtoQ, bsqi, pmin);
    finish_kernel<<<N_PTS / 256, 256, 0, stream>>>(a_sq, pmin, (float*)d_out);
}